// Round 13
// baseline (648.379 us; speedup 1.0000x reference)
//
#include <hip/hip_runtime.h>
#include <math.h>

#define NB 2048
#define PM_STAGE 2097152   // elements per pmeans stage (2048*16*2*32)
#define BPK_L    81920     // elements per packed weight layer (10*16*64*8)

typedef float    f32x4 __attribute__((ext_vector_type(4)));
typedef _Float16 f16x8 __attribute__((ext_vector_type(8)));

__device__ __forceinline__ float fast_tanh(float x) {
    float ax = fabsf(x);
    float e  = __expf(2.0f * ax);
    float t  = 1.0f - 2.0f / (e + 1.0f);
    return copysignf(t, x);
}

__device__ __forceinline__ void split16(float x, _Float16& hi, _Float16& lo) {
    hi = (_Float16)x;
    lo = (_Float16)(x - (float)hi);
}

// ---------------------------------------------------------------------------
// One-time weight pack -> f16 hi/lo B-fragments for the PER-ELECTRON part only
// (A-features: [s 0..255 | pu 256..287 | pd 288..319] -> W rows f / 768+ / 800+).
// Bpk[l][kc(10)][nt(16)][lane(64)][j(8)]; layers 0..3 = sW[l], 4 = vW.
// ---------------------------------------------------------------------------
__global__ __launch_bounds__(256) void k_prep_w(
    const float* __restrict__ sW, const float* __restrict__ vW,
    _Float16* __restrict__ Bhi, _Float16* __restrict__ Blo)
{
    const int blk = blockIdx.x;       // l*10 + kc
    const int l   = blk / 10;
    const int kc  = blk % 10;
    const float* Wsrc = (l < 4) ? (sW + (size_t)l * 212992) : vW;
    const int lane = threadIdx.x & 63;
    const int sub  = threadIdx.x >> 6;
    const size_t base = (size_t)l * BPK_L + (size_t)kc * 8192;
#pragma unroll
    for (int ntl = 0; ntl < 4; ++ntl) {
        const int nt = sub * 4 + ntl;
        const int n  = nt * 16 + (lane & 15);
#pragma unroll
        for (int j = 0; j < 8; ++j) {
            const int f = kc * 32 + (lane >> 4) * 8 + j;   // 0..319
            int row;
            if (f < 256)      row = f;
            else if (f < 288) row = 768 + (f - 256);
            else              row = 800 + (f - 288);
            const float w = Wsrc[row * 256 + n];
            _Float16 hi, lo; split16(w, hi, lo);
            Bhi[base + (size_t)(nt * 64 + lane) * 8 + j] = hi;
            Blo[base + (size_t)(nt * 64 + lane) * 8 + j] = lo;
        }
    }
}

// ---------------------------------------------------------------------------
// One-time p-layer weight pack: pW (4,32,32) -> f16 hi/lo B-frags
// ---------------------------------------------------------------------------
__global__ __launch_bounds__(128) void k_prep_p(
    const float* __restrict__ pW,
    _Float16* __restrict__ pBhi, _Float16* __restrict__ pBlo)
{
    const int l    = blockIdx.x;
    const int nt   = threadIdx.x >> 6;
    const int lane = threadIdx.x & 63;
    const int m16  = lane & 15, quad = lane >> 4;
#pragma unroll
    for (int j = 0; j < 8; ++j) {
        float w = pW[l * 1024 + (quad * 8 + j) * 32 + nt * 16 + m16];
        _Float16 hi, lo; split16(w, hi, lo);
        pBhi[((size_t)l * 2 + nt) * 512 + lane * 8 + j] = hi;
        pBlo[((size_t)l * 2 + nt) * 512 + lane * 8 + j] = lo;
    }
}

// ---------------------------------------------------------------------------
// p-stream via split-f16 MFMA (3-term). R11-VERBATIM (1024 threads, 16 waves,
// wave = m-tile). R12's 512-thread rewrite correlated with an absmax-3.0
// failure (pm-corruption signature) — reverted pending attribution.
// State pst[feat][pair] in LDS; residual pcur fp32 in regs in D-layout.
// pm output f16 hi/lo. pmeans per stage: (B,16(j),2(h),32).
// ---------------------------------------------------------------------------
__global__ __launch_bounds__(1024) void k_pstream(
    const float* __restrict__ r,
    const float* __restrict__ pW0, const float* __restrict__ pb0,
    const float* __restrict__ pb,
    const _Float16* __restrict__ pBhi, const _Float16* __restrict__ pBlo,
    _Float16* __restrict__ pm_hi, _Float16* __restrict__ pm_lo)
{
    const int b    = blockIdx.x;
    const int tid  = threadIdx.x;
    const int lane = tid & 63;
    const int wv   = __builtin_amdgcn_readfirstlane(tid >> 6);  // m-tile 0..15
    const int m16  = lane & 15;
    const int quad = lane >> 4;

    __shared__ float rl[48];
    __shared__ float pst[32][257];

    if (tid < 48) rl[tid] = r[b * 48 + tid];
    __syncthreads();

    const int f0 = m16, f1 = m16 + 16;
    float pcur[2][4];   // [nt][reg], D-layout residual state

    // ---- layer 0
#pragma unroll
    for (int reg = 0; reg < 4; ++reg) {
        const int pair = wv * 16 + quad * 4 + reg;
        const int i = pair >> 4, j = pair & 15;
        float dx = rl[j * 3 + 0] - rl[i * 3 + 0];
        float dy = rl[j * 3 + 1] - rl[i * 3 + 1];
        float dz = rl[j * 3 + 2] - rl[i * 3 + 2];
        float ee = (i == j) ? 1.0f : 0.0f;
        float len = sqrtf((dx + ee) * (dx + ee) + (dy + ee) * (dy + ee) + (dz + ee) * (dz + ee));
#pragma unroll
        for (int nt = 0; nt < 2; ++nt) {
            const int k = nt ? f1 : f0;
            float acc = pb0[k] + dx * pW0[k] + dy * pW0[32 + k]
                      + dz * pW0[64 + k] + len * pW0[96 + k];
            float v = fast_tanh(acc);
            pcur[nt][reg] = v;
            pst[k][pair] = v;
        }
    }
    __syncthreads();

    // ---- stage-0 means
    {
        const int o = tid, mj = o >> 6, mh = (o >> 5) & 1, mk = o & 31;
        float s = 0.f;
#pragma unroll
        for (int i8 = 0; i8 < 8; ++i8) s += pst[mk][(mh * 8 + i8) * 16 + mj];
        _Float16 hi, lo; split16(s * 0.125f, hi, lo);
        pm_hi[(size_t)b * 1024 + o] = hi;
        pm_lo[(size_t)b * 1024 + o] = lo;
    }

    const int apair = wv * 16 + m16;
    for (int l = 0; l < 4; ++l) {
        f16x8 ah, al;
#pragma unroll
        for (int jj = 0; jj < 8; ++jj) {
            float v = pst[quad * 8 + jj][apair];
            _Float16 hi, lo; split16(v, hi, lo);
            ah[jj] = hi; al[jj] = lo;
        }
        const _Float16* bhp = pBhi + ((size_t)l * 2) * 512 + (size_t)lane * 8;
        const _Float16* blp = pBlo + ((size_t)l * 2) * 512 + (size_t)lane * 8;
        f32x4 acc0 = (f32x4){0.f, 0.f, 0.f, 0.f};
        f32x4 acc1 = (f32x4){0.f, 0.f, 0.f, 0.f};
        {
            f16x8 bh = *(const f16x8*)(bhp);
            f16x8 bl = *(const f16x8*)(blp);
            acc0 = __builtin_amdgcn_mfma_f32_16x16x32_f16(ah, bh, acc0, 0, 0, 0);
            acc0 = __builtin_amdgcn_mfma_f32_16x16x32_f16(ah, bl, acc0, 0, 0, 0);
            acc0 = __builtin_amdgcn_mfma_f32_16x16x32_f16(al, bh, acc0, 0, 0, 0);
            bh = *(const f16x8*)(bhp + 512);
            bl = *(const f16x8*)(blp + 512);
            acc1 = __builtin_amdgcn_mfma_f32_16x16x32_f16(ah, bh, acc1, 0, 0, 0);
            acc1 = __builtin_amdgcn_mfma_f32_16x16x32_f16(ah, bl, acc1, 0, 0, 0);
            acc1 = __builtin_amdgcn_mfma_f32_16x16x32_f16(al, bh, acc1, 0, 0, 0);
        }
        const float b0v = pb[l * 32 + f0];
        const float b1v = pb[l * 32 + f1];
        __syncthreads();   // all reads of old pst complete
#pragma unroll
        for (int reg = 0; reg < 4; ++reg) {
            const int pair = wv * 16 + quad * 4 + reg;
            pcur[0][reg] += fast_tanh(acc0[reg] + b0v);
            pcur[1][reg] += fast_tanh(acc1[reg] + b1v);
            pst[f0][pair] = pcur[0][reg];
            pst[f1][pair] = pcur[1][reg];
        }
        __syncthreads();   // new pst visible
        {
            const int o = tid, mj = o >> 6, mh = (o >> 5) & 1, mk = o & 31;
            float s = 0.f;
#pragma unroll
            for (int i8 = 0; i8 < 8; ++i8) s += pst[mk][(mh * 8 + i8) * 16 + mj];
            _Float16 hi, lo; split16(s * 0.125f, hi, lo);
            pm_hi[(size_t)(l + 1) * PM_STAGE + (size_t)b * 1024 + o] = hi;
            pm_lo[(size_t)(l + 1) * PM_STAGE + (size_t)b * 1024 + o] = lo;
        }
    }
}

// ---------------------------------------------------------------------------
// Layer 0: embedding + first s layer (fp32). Writes s hi/lo (f16).
// ---------------------------------------------------------------------------
__global__ __launch_bounds__(256) void k_s0(
    const float* __restrict__ r, const float* __restrict__ a,
    const float* __restrict__ sW0, const float* __restrict__ sb0,
    _Float16* __restrict__ s_hi, _Float16* __restrict__ s_lo)
{
    const int b   = blockIdx.x;
    const int tid = threadIdx.x;
    __shared__ float rl[48];
    __shared__ float al[12];
    __shared__ float pin[16][16][4];
    __shared__ float se[16][16];
    __shared__ float sm0[2][16];
    __shared__ float pm0[16][2][4];
    __shared__ float blk[16][56];

    if (tid < 48) rl[tid] = r[b * 48 + tid];
    if (tid >= 64 && tid < 76) al[tid - 64] = a[tid - 64];
    __syncthreads();
    {
        const int i = tid & 15, j = tid >> 4;
        float dx = rl[j * 3 + 0] - rl[i * 3 + 0];
        float dy = rl[j * 3 + 1] - rl[i * 3 + 1];
        float dz = rl[j * 3 + 2] - rl[i * 3 + 2];
        float ee = (i == j) ? 1.0f : 0.0f;
        float len = sqrtf((dx + ee) * (dx + ee) + (dy + ee) * (dy + ee) + (dz + ee) * (dz + ee));
        pin[j][i][0] = dx; pin[j][i][1] = dy; pin[j][i][2] = dz; pin[j][i][3] = len;
    }
    if (tid < 16) {
        const int e = tid;
#pragma unroll
        for (int at = 0; at < 4; ++at) {
            float dx = rl[e * 3 + 0] - al[at * 3 + 0];
            float dy = rl[e * 3 + 1] - al[at * 3 + 1];
            float dz = rl[e * 3 + 2] - al[at * 3 + 2];
            float ln = sqrtf(dx * dx + dy * dy + dz * dz);
            se[e][at * 4 + 0] = dx; se[e][at * 4 + 1] = dy;
            se[e][at * 4 + 2] = dz; se[e][at * 4 + 3] = ln;
        }
    }
    __syncthreads();
    if (tid < 32) {
        const int h = tid >> 4, f = tid & 15;
        float s = 0.f;
        for (int e = 0; e < 8; ++e) s += se[h * 8 + e][f];
        sm0[h][f] = s * 0.125f;
    }
    if (tid < 128) {
        const int j = tid >> 3, h = (tid >> 2) & 1, f = tid & 3;
        float s = 0.f;
        for (int i2 = 0; i2 < 8; ++i2) s += pin[j][h * 8 + i2][f];
        pm0[j][h][f] = s * 0.125f;
    }
    __syncthreads();
    for (int t = tid; t < 16 * 56; t += 256) {
        const int e = t / 56, k = t % 56;
        float v;
        if (k < 16)      v = se[e][k];
        else if (k < 32) v = sm0[0][k - 16];
        else if (k < 48) v = sm0[1][k - 32];
        else if (k < 52) v = pm0[e][0][k - 48];
        else             v = pm0[e][1][k - 52];
        blk[e][k] = v;
    }
    __syncthreads();

    const int n = tid;
    float acc[16];
#pragma unroll
    for (int e = 0; e < 16; ++e) acc[e] = sb0[n];
    for (int k = 0; k < 56; k += 4) {
        float w0 = sW0[(k + 0) * 256 + n];
        float w1 = sW0[(k + 1) * 256 + n];
        float w2 = sW0[(k + 2) * 256 + n];
        float w3 = sW0[(k + 3) * 256 + n];
#pragma unroll
        for (int e = 0; e < 16; ++e) {
            float4 s4 = *(const float4*)&blk[e][k];
            acc[e] += s4.x * w0 + s4.y * w1 + s4.z * w2 + s4.w * w3;
        }
    }
    _Float16* sh_b = s_hi + (size_t)b * 4096;
    _Float16* sl_b = s_lo + (size_t)b * 4096;
#pragma unroll
    for (int e = 0; e < 16; ++e) {
        float v = fast_tanh(acc[e]);
        _Float16 hi, lo; split16(v, hi, lo);
        sh_b[e * 256 + n] = hi;
        sl_b[e * 256 + n] = lo;
    }
}

// ---------------------------------------------------------------------------
// Shared (row-constant) part, exact fp32:
//   Zsh[b][n] = bias[n] + mu_b . W[256:512][:,n] + md_b . W[512:768][:,n]
// Block = 4 walkers, 256 threads, grid 512.
// ---------------------------------------------------------------------------
__global__ __launch_bounds__(256) void k_shared(
    const _Float16* __restrict__ s_hi, const _Float16* __restrict__ s_lo,
    const float* __restrict__ W, const float* __restrict__ bias,
    float* __restrict__ Zsh)
{
    const int b0  = blockIdx.x * 4;
    const int tid = threadIdx.x;
    __shared__ float mean[4][2][256];   // 8 KB

    {
        const int v0 = tid * 8;          // covers 4*2*256 = 2048 outputs
        const int w  = v0 >> 9, h = (v0 >> 8) & 1, k0 = v0 & 255;
        float acc[8] = {0.f, 0.f, 0.f, 0.f, 0.f, 0.f, 0.f, 0.f};
        for (int e = 0; e < 8; ++e) {
            const size_t base = ((size_t)(b0 + w) * 16 + h * 8 + e) * 256 + k0;
#pragma unroll
            for (int kk = 0; kk < 8; ++kk)
                acc[kk] += (float)s_hi[base + kk] + (float)s_lo[base + kk];
        }
#pragma unroll
        for (int kk = 0; kk < 8; ++kk) mean[w][h][k0 + kk] = acc[kk] * 0.125f;
    }
    __syncthreads();

    const int w2 = tid >> 6;
    const int n0 = (tid & 63) * 4;
    float4 z = make_float4(bias[n0], bias[n0 + 1], bias[n0 + 2], bias[n0 + 3]);
#pragma unroll 4
    for (int k = 0; k < 256; ++k) {
        const float mu = mean[w2][0][k];
        const float md = mean[w2][1][k];
        float4 wmu = *(const float4*)&W[(256 + k) * 256 + n0];
        float4 wmd = *(const float4*)&W[(512 + k) * 256 + n0];
        z.x += mu * wmu.x + md * wmd.x;
        z.y += mu * wmu.y + md * wmd.y;
        z.z += mu * wmu.z + md * wmd.z;
        z.w += mu * wmu.w + md * wmd.w;
    }
    *(float4*)&Zsh[(size_t)(b0 + w2) * 256 + n0] = z;
}

// ---------------------------------------------------------------------------
// Split-f16 MFMA s-layer (per-electron part, K=320), 3-term split.
// Block = 4 walkers, 512 threads = 8 waves = 2 wave-groups; both wave-groups
// stream the same B addresses (L1 dedup); grid 512. (R11-verbatim)
// ---------------------------------------------------------------------------
__global__ __launch_bounds__(512, 4) void k_gemm(
    _Float16* __restrict__ s_hi, _Float16* __restrict__ s_lo,
    const _Float16* __restrict__ pm_hi, const _Float16* __restrict__ pm_lo,
    const _Float16* __restrict__ Bhi, const _Float16* __restrict__ Blo,
    const float* __restrict__ Zsh,
    int is_final)
{
    const int tid  = threadIdx.x;
    const int lane = tid & 63;
    const int wv   = tid >> 6;        // 0..7
    const int wg   = wv >> 2;         // walker group (2 walkers each)
    const int wv4  = wv & 3;          // n-tile group
    const int m16  = lane & 15;
    const int quad = lane >> 4;
    const int wb   = blockIdx.x * 4 + wg * 2;
    const int n0   = wv4 * 64;

    f32x4 acc[2][4];
#pragma unroll
    for (int mt = 0; mt < 2; ++mt)
#pragma unroll
        for (int nt = 0; nt < 4; ++nt) acc[mt][nt] = (f32x4){0.f, 0.f, 0.f, 0.f};

    int aS[2], aP[2];
#pragma unroll
    for (int mt = 0; mt < 2; ++mt) {
        aS[mt] = ((wb + mt) * 16 + m16) * 256 + quad * 8;
        aP[mt] = ((wb + mt) * 16 + m16) * 64  + quad * 8;
    }
    const _Float16* Bhw = Bhi + (size_t)(wv4 * 4) * 512 + (size_t)lane * 8;
    const _Float16* Blw = Blo + (size_t)(wv4 * 4) * 512 + (size_t)lane * 8;

    // ---- s part: kc 0..7
#pragma unroll
    for (int kc = 0; kc < 8; ++kc) {
        f16x8 ah[2], al[2];
#pragma unroll
        for (int mt = 0; mt < 2; ++mt) {
            ah[mt] = *(const f16x8*)(s_hi + aS[mt] + kc * 32);
            al[mt] = *(const f16x8*)(s_lo + aS[mt] + kc * 32);
        }
#pragma unroll
        for (int nt = 0; nt < 4; ++nt) {
            f16x8 bh = *(const f16x8*)(Bhw + (size_t)kc * 8192 + nt * 512);
            f16x8 bl = *(const f16x8*)(Blw + (size_t)kc * 8192 + nt * 512);
#pragma unroll
            for (int mt = 0; mt < 2; ++mt) {
                acc[mt][nt] = __builtin_amdgcn_mfma_f32_16x16x32_f16(ah[mt], bh, acc[mt][nt], 0, 0, 0);
                acc[mt][nt] = __builtin_amdgcn_mfma_f32_16x16x32_f16(ah[mt], bl, acc[mt][nt], 0, 0, 0);
                acc[mt][nt] = __builtin_amdgcn_mfma_f32_16x16x32_f16(al[mt], bh, acc[mt][nt], 0, 0, 0);
            }
        }
    }
    // ---- p part: kc 8..9 (pu, pd), pm hi/lo 3-term
#pragma unroll
    for (int h = 0; h < 2; ++h) {
        f16x8 ah[2], al[2];
#pragma unroll
        for (int mt = 0; mt < 2; ++mt) {
            ah[mt] = *(const f16x8*)(pm_hi + aP[mt] + h * 32);
            al[mt] = *(const f16x8*)(pm_lo + aP[mt] + h * 32);
        }
#pragma unroll
        for (int nt = 0; nt < 4; ++nt) {
            f16x8 bh = *(const f16x8*)(Bhw + (size_t)(8 + h) * 8192 + nt * 512);
            f16x8 bl = *(const f16x8*)(Blw + (size_t)(8 + h) * 8192 + nt * 512);
#pragma unroll
            for (int mt = 0; mt < 2; ++mt) {
                acc[mt][nt] = __builtin_amdgcn_mfma_f32_16x16x32_f16(ah[mt], bh, acc[mt][nt], 0, 0, 0);
                acc[mt][nt] = __builtin_amdgcn_mfma_f32_16x16x32_f16(ah[mt], bl, acc[mt][nt], 0, 0, 0);
                acc[mt][nt] = __builtin_amdgcn_mfma_f32_16x16x32_f16(al[mt], bh, acc[mt][nt], 0, 0, 0);
            }
        }
    }

    __syncthreads();   // all A reads complete before in-place rewrite

    // ---- epilogue
#pragma unroll
    for (int mt = 0; mt < 2; ++mt) {
#pragma unroll
        for (int nt = 0; nt < 4; ++nt) {
            const int n  = n0 + nt * 16 + m16;
            const float zv = Zsh[(size_t)(wb + mt) * 256 + n];
            const int rowbase = (wb + mt) * 16 + quad * 4;
#pragma unroll
            for (int reg = 0; reg < 4; ++reg) {
                const int idx = (rowbase + reg) * 256 + n;
                float t = fast_tanh(acc[mt][nt][reg] + zv);
                if (!is_final) t += (float)s_hi[idx] + (float)s_lo[idx];
                _Float16 hi, lo; split16(t, hi, lo);
                s_hi[idx] = hi;
                s_lo[idx] = lo;
            }
        }
    }
}

// ---------------------------------------------------------------------------
// FUSED orbitals + slogdet + logsumexp. Block = 1 walker, 256 threads.
// Orbitals -> LDS orbL[spin][det][68] (no 16.8 MB global round-trip);
// threads 0-15 then do both spins' 8x8 slogdet + det-combine (shuffles
// confined to lanes 0-15 of wave 0).
// ---------------------------------------------------------------------------
__device__ __forceinline__ void slogdet8(float M[8][8], float& sgn_out, float& ld_out) {
    float sgn = 1.f, ld = 0.f;
#pragma unroll
    for (int k = 0; k < 8; ++k) {
        float best = fabsf(M[k][k]);
        int p = k;
#pragma unroll
        for (int rr = k + 1; rr < 8; ++rr) {
            float v = fabsf(M[rr][k]);
            if (v > best) { best = v; p = rr; }
        }
        if (p != k) sgn = -sgn;
#pragma unroll
        for (int rr = k + 1; rr < 8; ++rr) {
            bool sw = (rr == p);
#pragma unroll
            for (int cc = k; cc < 8; ++cc) {
                float x = M[k][cc], y = M[rr][cc];
                M[k][cc]  = sw ? y : x;
                M[rr][cc] = sw ? x : y;
            }
        }
        float piv = M[k][k];
        if (piv < 0.f) sgn = -sgn;
        ld += logf(fabsf(piv));
        float inv = 1.f / piv;
#pragma unroll
        for (int rr = k + 1; rr < 8; ++rr) {
            float f = M[rr][k] * inv;
#pragma unroll
            for (int cc = k + 1; cc < 8; ++cc) M[rr][cc] -= f * M[k][cc];
        }
    }
    sgn_out = sgn; ld_out = ld;
}

__global__ __launch_bounds__(256) void k_orbdet(
    const float* __restrict__ r, const float* __restrict__ a,
    const _Float16* __restrict__ s_hi, const _Float16* __restrict__ s_lo,
    const float* __restrict__ wuW, const float* __restrict__ wub,
    const float* __restrict__ wdW, const float* __restrict__ wdb,
    const float* __restrict__ wfW,
    float* __restrict__ out)
{
    const int b   = blockIdx.x;
    const int tid = threadIdx.x;
    __shared__ float sF[16][256];
    __shared__ float envl[16];
    __shared__ float orbL[2][16][68];
    {
        const _Float16* sh = s_hi + (size_t)b * 4096;
        const _Float16* sl = s_lo + (size_t)b * 4096;
        float* sFF = &sF[0][0];
        for (int t = tid; t < 4096; t += 256)
            sFF[t] = (float)sh[t] + (float)sl[t];
    }
    if (tid < 16) {
        float ex = 0.f;
#pragma unroll
        for (int at = 0; at < 4; ++at) {
            float dx = r[b * 48 + tid * 3 + 0] - a[at * 3 + 0];
            float dy = r[b * 48 + tid * 3 + 1] - a[at * 3 + 1];
            float dz = r[b * 48 + tid * 3 + 2] - a[at * 3 + 2];
            ex += __expf(-sqrtf(dx * dx + dy * dy + dz * dz));
        }
        envl[tid] = ex;
    }
    __syncthreads();

    // ---- orbitals: thread = (spin, col c); c = jrow*16 + det
    {
        const int spin = tid >> 7;
        const int c    = tid & 127;
        const float* Wm = spin ? wdW : wuW;
        const float* bm = spin ? wdb : wub;
        const int e0 = spin * 8;
        float acc[8];
        const float bias = bm[c];
#pragma unroll
        for (int e = 0; e < 8; ++e) acc[e] = bias;
        for (int k = 0; k < 256; k += 4) {
            float w0 = Wm[(k + 0) * 128 + c];
            float w1 = Wm[(k + 1) * 128 + c];
            float w2 = Wm[(k + 2) * 128 + c];
            float w3 = Wm[(k + 3) * 128 + c];
#pragma unroll
            for (int e = 0; e < 8; ++e) {
                float4 s4 = *(const float4*)&sF[e0 + e][k];
                acc[e] += s4.x * w0 + s4.y * w1 + s4.z * w2 + s4.w * w3;
            }
        }
        const int d = c & 15, jrow = c >> 4;
#pragma unroll
        for (int e = 0; e < 8; ++e)
            orbL[spin][d][jrow * 8 + e] = acc[e] * envl[e0 + e];
    }
    __syncthreads();

    // ---- determinants: threads 0-15 (wave 0), one det each
    if (tid < 16) {
        const int d = tid;
        float M[8][8];
#pragma unroll
        for (int rr = 0; rr < 8; ++rr)
#pragma unroll
            for (int cc = 0; cc < 8; ++cc) M[rr][cc] = orbL[0][d][rr * 8 + cc];
        float s1, l1; slogdet8(M, s1, l1);
#pragma unroll
        for (int rr = 0; rr < 8; ++rr)
#pragma unroll
            for (int cc = 0; cc < 8; ++cc) M[rr][cc] = orbL[1][d][rr * 8 + cc];
        float s2, l2; slogdet8(M, s2, l2);
        float sgn = s1 * s2;
        float ld  = l1 + l2;

        float m = ld;
        m = fmaxf(m, __shfl_xor(m, 1));
        m = fmaxf(m, __shfl_xor(m, 2));
        m = fmaxf(m, __shfl_xor(m, 4));
        m = fmaxf(m, __shfl_xor(m, 8));
        float sub = sgn * __expf(ld - m) * wfW[d];
        sub += __shfl_xor(sub, 1);
        sub += __shfl_xor(sub, 2);
        sub += __shfl_xor(sub, 4);
        sub += __shfl_xor(sub, 8);
        if (d == 0) out[b] = logf(fabsf(sub)) + m;
    }
}

// ---------------------------------------------------------------------------
extern "C" void kernel_launch(void* const* d_in, const int* in_sizes, int n_in,
                              void* d_out, int out_size, void* d_ws, size_t ws_size,
                              hipStream_t stream) {
    (void)in_sizes; (void)n_in; (void)out_size; (void)ws_size;
    const float* r   = (const float*)d_in[0];
    const float* a   = (const float*)d_in[1];
    const float* sW0 = (const float*)d_in[2];
    const float* sb0 = (const float*)d_in[3];
    const float* sW  = (const float*)d_in[4];
    const float* sb  = (const float*)d_in[5];
    const float* pW0 = (const float*)d_in[6];
    const float* pb0 = (const float*)d_in[7];
    const float* pW  = (const float*)d_in[8];
    const float* pb  = (const float*)d_in[9];
    const float* vW  = (const float*)d_in[10];
    const float* vb  = (const float*)d_in[11];
    const float* wuW = (const float*)d_in[12];
    const float* wub = (const float*)d_in[13];
    const float* wdW = (const float*)d_in[14];
    const float* wdb = (const float*)d_in[15];
    const float* wfW = (const float*)d_in[16];
    float* out = (float*)d_out;

    // workspace layout (bytes), total 79,249,408 (< 79,691,776 known-safe)
    char* wsb = (char*)d_ws;
    _Float16* s_hi  = (_Float16*)(wsb + 0);          // 16,777,216
    _Float16* s_lo  = (_Float16*)(wsb + 16777216);   // 16,777,216
    _Float16* pm_hi = (_Float16*)(wsb + 33554432);   // 20,971,520 (5 stages)
    _Float16* pm_lo = (_Float16*)(wsb + 54525952);   // 20,971,520
    float*    Zsh   = (float*)   (wsb + 75497472);   //  2,097,152
    _Float16* Bhi   = (_Float16*)(wsb + 77594624);   //    819,200
    _Float16* Blo   = (_Float16*)(wsb + 78413824);   //    819,200
    _Float16* pBhi  = (_Float16*)(wsb + 79233024);   //      8,192
    _Float16* pBlo  = (_Float16*)(wsb + 79241216);   //      8,192

    k_prep_w<<<50, 256, 0, stream>>>(sW, vW, Bhi, Blo);
    k_prep_p<<<4, 128, 0, stream>>>(pW, pBhi, pBlo);
    k_pstream<<<NB, 1024, 0, stream>>>(r, pW0, pb0, pb, pBhi, pBlo, pm_hi, pm_lo);
    k_s0<<<NB, 256, 0, stream>>>(r, a, sW0, sb0, s_hi, s_lo);
    for (int l = 0; l < 4; ++l) {
        k_shared<<<NB / 4, 256, 0, stream>>>(s_hi, s_lo, sW + (size_t)l * 212992,
                                             sb + l * 256, Zsh);
        k_gemm<<<NB / 4, 512, 0, stream>>>(s_hi, s_lo,
                                           pm_hi + (size_t)l * PM_STAGE,
                                           pm_lo + (size_t)l * PM_STAGE,
                                           Bhi + (size_t)l * BPK_L,
                                           Blo + (size_t)l * BPK_L,
                                           Zsh, 0);
    }
    k_shared<<<NB / 4, 256, 0, stream>>>(s_hi, s_lo, vW, vb, Zsh);
    k_gemm<<<NB / 4, 512, 0, stream>>>(s_hi, s_lo,
                                       pm_hi + (size_t)4 * PM_STAGE,
                                       pm_lo + (size_t)4 * PM_STAGE,
                                       Bhi + (size_t)4 * BPK_L,
                                       Blo + (size_t)4 * BPK_L,
                                       Zsh, 1);
    k_orbdet<<<NB, 256, 0, stream>>>(r, a, s_hi, s_lo, wuW, wub, wdW, wdb, wfW, out);
}

// Round 14
// 611.670 us; speedup vs baseline: 1.0600x; 1.0600x over previous
//
#include <hip/hip_runtime.h>
#include <math.h>

#define NB 2048
#define PM_STAGE 2097152   // elements per pmeans stage (2048*16*2*32)
#define BPK_L    81920     // elements per packed weight layer (10*16*64*8)

typedef float    f32x4 __attribute__((ext_vector_type(4)));
typedef _Float16 f16x8 __attribute__((ext_vector_type(8)));

__device__ __forceinline__ float fast_tanh(float x) {
    float ax = fabsf(x);
    float e  = __expf(2.0f * ax);
    float t  = 1.0f - 2.0f / (e + 1.0f);
    return copysignf(t, x);
}

__device__ __forceinline__ void split16(float x, _Float16& hi, _Float16& lo) {
    hi = (_Float16)x;
    lo = (_Float16)(x - (float)hi);
}

// ---------------------------------------------------------------------------
// One-time weight pack -> f16 hi/lo B-fragments for the PER-ELECTRON part only
// (A-features: [s 0..255 | pu 256..287 | pd 288..319] -> W rows f / 768+ / 800+).
// Bpk[l][kc(10)][nt(16)][lane(64)][j(8)]; layers 0..3 = sW[l], 4 = vW.
// ---------------------------------------------------------------------------
__global__ __launch_bounds__(256) void k_prep_w(
    const float* __restrict__ sW, const float* __restrict__ vW,
    _Float16* __restrict__ Bhi, _Float16* __restrict__ Blo)
{
    const int blk = blockIdx.x;       // l*10 + kc
    const int l   = blk / 10;
    const int kc  = blk % 10;
    const float* Wsrc = (l < 4) ? (sW + (size_t)l * 212992) : vW;
    const int lane = threadIdx.x & 63;
    const int sub  = threadIdx.x >> 6;
    const size_t base = (size_t)l * BPK_L + (size_t)kc * 8192;
#pragma unroll
    for (int ntl = 0; ntl < 4; ++ntl) {
        const int nt = sub * 4 + ntl;
        const int n  = nt * 16 + (lane & 15);
#pragma unroll
        for (int j = 0; j < 8; ++j) {
            const int f = kc * 32 + (lane >> 4) * 8 + j;   // 0..319
            int row;
            if (f < 256)      row = f;
            else if (f < 288) row = 768 + (f - 256);
            else              row = 800 + (f - 288);
            const float w = Wsrc[row * 256 + n];
            _Float16 hi, lo; split16(w, hi, lo);
            Bhi[base + (size_t)(nt * 64 + lane) * 8 + j] = hi;
            Blo[base + (size_t)(nt * 64 + lane) * 8 + j] = lo;
        }
    }
}

// ---------------------------------------------------------------------------
// One-time p-layer weight pack: pW (4,32,32) -> f16 hi/lo B-frags
// ---------------------------------------------------------------------------
__global__ __launch_bounds__(128) void k_prep_p(
    const float* __restrict__ pW,
    _Float16* __restrict__ pBhi, _Float16* __restrict__ pBlo)
{
    const int l    = blockIdx.x;
    const int nt   = threadIdx.x >> 6;
    const int lane = threadIdx.x & 63;
    const int m16  = lane & 15, quad = lane >> 4;
#pragma unroll
    for (int j = 0; j < 8; ++j) {
        float w = pW[l * 1024 + (quad * 8 + j) * 32 + nt * 16 + m16];
        _Float16 hi, lo; split16(w, hi, lo);
        pBhi[((size_t)l * 2 + nt) * 512 + lane * 8 + j] = hi;
        pBlo[((size_t)l * 2 + nt) * 512 + lane * 8 + j] = lo;
    }
}

// ---------------------------------------------------------------------------
// One-time orbital weight pack: wuW/wdW (256,128) -> f16 hi/lo B-frags.
// oB[spin][kc(8)][nt(8)][lane(64)][j(8)]:
//   lane holds B[k = kc*32 + (lane>>4)*8 + j][n = nt*16 + (lane&15)].
// ---------------------------------------------------------------------------
__global__ __launch_bounds__(256) void k_prep_orb(
    const float* __restrict__ wuW, const float* __restrict__ wdW,
    _Float16* __restrict__ oBhi, _Float16* __restrict__ oBlo)
{
    const int blk  = blockIdx.x;      // spin*8 + kc
    const int spin = blk >> 3, kc = blk & 7;
    const float* W = spin ? wdW : wuW;
    const int lane = threadIdx.x & 63;
    const int sub  = threadIdx.x >> 6;   // 0..3 -> nt = sub*2, sub*2+1
#pragma unroll
    for (int t = 0; t < 2; ++t) {
        const int nt = sub * 2 + t;
        const int n  = nt * 16 + (lane & 15);
#pragma unroll
        for (int j = 0; j < 8; ++j) {
            const int k = kc * 32 + (lane >> 4) * 8 + j;
            float w = W[k * 128 + n];
            _Float16 hi, lo; split16(w, hi, lo);
            const size_t o = (((size_t)spin * 8 + kc) * 8 + nt) * 512 + (size_t)lane * 8 + j;
            oBhi[o] = hi; oBlo[o] = lo;
        }
    }
}

// ---------------------------------------------------------------------------
// p-stream via split-f16 MFMA (3-term). R11-VERBATIM (frozen: verified).
// ---------------------------------------------------------------------------
__global__ __launch_bounds__(1024) void k_pstream(
    const float* __restrict__ r,
    const float* __restrict__ pW0, const float* __restrict__ pb0,
    const float* __restrict__ pb,
    const _Float16* __restrict__ pBhi, const _Float16* __restrict__ pBlo,
    _Float16* __restrict__ pm_hi, _Float16* __restrict__ pm_lo)
{
    const int b    = blockIdx.x;
    const int tid  = threadIdx.x;
    const int lane = tid & 63;
    const int wv   = __builtin_amdgcn_readfirstlane(tid >> 6);  // m-tile 0..15
    const int m16  = lane & 15;
    const int quad = lane >> 4;

    __shared__ float rl[48];
    __shared__ float pst[32][257];

    if (tid < 48) rl[tid] = r[b * 48 + tid];
    __syncthreads();

    const int f0 = m16, f1 = m16 + 16;
    float pcur[2][4];   // [nt][reg], D-layout residual state

    // ---- layer 0
#pragma unroll
    for (int reg = 0; reg < 4; ++reg) {
        const int pair = wv * 16 + quad * 4 + reg;
        const int i = pair >> 4, j = pair & 15;
        float dx = rl[j * 3 + 0] - rl[i * 3 + 0];
        float dy = rl[j * 3 + 1] - rl[i * 3 + 1];
        float dz = rl[j * 3 + 2] - rl[i * 3 + 2];
        float ee = (i == j) ? 1.0f : 0.0f;
        float len = sqrtf((dx + ee) * (dx + ee) + (dy + ee) * (dy + ee) + (dz + ee) * (dz + ee));
#pragma unroll
        for (int nt = 0; nt < 2; ++nt) {
            const int k = nt ? f1 : f0;
            float acc = pb0[k] + dx * pW0[k] + dy * pW0[32 + k]
                      + dz * pW0[64 + k] + len * pW0[96 + k];
            float v = fast_tanh(acc);
            pcur[nt][reg] = v;
            pst[k][pair] = v;
        }
    }
    __syncthreads();

    // ---- stage-0 means
    {
        const int o = tid, mj = o >> 6, mh = (o >> 5) & 1, mk = o & 31;
        float s = 0.f;
#pragma unroll
        for (int i8 = 0; i8 < 8; ++i8) s += pst[mk][(mh * 8 + i8) * 16 + mj];
        _Float16 hi, lo; split16(s * 0.125f, hi, lo);
        pm_hi[(size_t)b * 1024 + o] = hi;
        pm_lo[(size_t)b * 1024 + o] = lo;
    }

    const int apair = wv * 16 + m16;
    for (int l = 0; l < 4; ++l) {
        f16x8 ah, al;
#pragma unroll
        for (int jj = 0; jj < 8; ++jj) {
            float v = pst[quad * 8 + jj][apair];
            _Float16 hi, lo; split16(v, hi, lo);
            ah[jj] = hi; al[jj] = lo;
        }
        const _Float16* bhp = pBhi + ((size_t)l * 2) * 512 + (size_t)lane * 8;
        const _Float16* blp = pBlo + ((size_t)l * 2) * 512 + (size_t)lane * 8;
        f32x4 acc0 = (f32x4){0.f, 0.f, 0.f, 0.f};
        f32x4 acc1 = (f32x4){0.f, 0.f, 0.f, 0.f};
        {
            f16x8 bh = *(const f16x8*)(bhp);
            f16x8 bl = *(const f16x8*)(blp);
            acc0 = __builtin_amdgcn_mfma_f32_16x16x32_f16(ah, bh, acc0, 0, 0, 0);
            acc0 = __builtin_amdgcn_mfma_f32_16x16x32_f16(ah, bl, acc0, 0, 0, 0);
            acc0 = __builtin_amdgcn_mfma_f32_16x16x32_f16(al, bh, acc0, 0, 0, 0);
            bh = *(const f16x8*)(bhp + 512);
            bl = *(const f16x8*)(blp + 512);
            acc1 = __builtin_amdgcn_mfma_f32_16x16x32_f16(ah, bh, acc1, 0, 0, 0);
            acc1 = __builtin_amdgcn_mfma_f32_16x16x32_f16(ah, bl, acc1, 0, 0, 0);
            acc1 = __builtin_amdgcn_mfma_f32_16x16x32_f16(al, bh, acc1, 0, 0, 0);
        }
        const float b0v = pb[l * 32 + f0];
        const float b1v = pb[l * 32 + f1];
        __syncthreads();   // all reads of old pst complete
#pragma unroll
        for (int reg = 0; reg < 4; ++reg) {
            const int pair = wv * 16 + quad * 4 + reg;
            pcur[0][reg] += fast_tanh(acc0[reg] + b0v);
            pcur[1][reg] += fast_tanh(acc1[reg] + b1v);
            pst[f0][pair] = pcur[0][reg];
            pst[f1][pair] = pcur[1][reg];
        }
        __syncthreads();   // new pst visible
        {
            const int o = tid, mj = o >> 6, mh = (o >> 5) & 1, mk = o & 31;
            float s = 0.f;
#pragma unroll
            for (int i8 = 0; i8 < 8; ++i8) s += pst[mk][(mh * 8 + i8) * 16 + mj];
            _Float16 hi, lo; split16(s * 0.125f, hi, lo);
            pm_hi[(size_t)(l + 1) * PM_STAGE + (size_t)b * 1024 + o] = hi;
            pm_lo[(size_t)(l + 1) * PM_STAGE + (size_t)b * 1024 + o] = lo;
        }
    }
}

// ---------------------------------------------------------------------------
// Layer 0: embedding + first s layer (fp32). Writes s hi/lo (f16).
// ---------------------------------------------------------------------------
__global__ __launch_bounds__(256) void k_s0(
    const float* __restrict__ r, const float* __restrict__ a,
    const float* __restrict__ sW0, const float* __restrict__ sb0,
    _Float16* __restrict__ s_hi, _Float16* __restrict__ s_lo)
{
    const int b   = blockIdx.x;
    const int tid = threadIdx.x;
    __shared__ float rl[48];
    __shared__ float al[12];
    __shared__ float pin[16][16][4];
    __shared__ float se[16][16];
    __shared__ float sm0[2][16];
    __shared__ float pm0[16][2][4];
    __shared__ float blk[16][56];

    if (tid < 48) rl[tid] = r[b * 48 + tid];
    if (tid >= 64 && tid < 76) al[tid - 64] = a[tid - 64];
    __syncthreads();
    {
        const int i = tid & 15, j = tid >> 4;
        float dx = rl[j * 3 + 0] - rl[i * 3 + 0];
        float dy = rl[j * 3 + 1] - rl[i * 3 + 1];
        float dz = rl[j * 3 + 2] - rl[i * 3 + 2];
        float ee = (i == j) ? 1.0f : 0.0f;
        float len = sqrtf((dx + ee) * (dx + ee) + (dy + ee) * (dy + ee) + (dz + ee) * (dz + ee));
        pin[j][i][0] = dx; pin[j][i][1] = dy; pin[j][i][2] = dz; pin[j][i][3] = len;
    }
    if (tid < 16) {
        const int e = tid;
#pragma unroll
        for (int at = 0; at < 4; ++at) {
            float dx = rl[e * 3 + 0] - al[at * 3 + 0];
            float dy = rl[e * 3 + 1] - al[at * 3 + 1];
            float dz = rl[e * 3 + 2] - al[at * 3 + 2];
            float ln = sqrtf(dx * dx + dy * dy + dz * dz);
            se[e][at * 4 + 0] = dx; se[e][at * 4 + 1] = dy;
            se[e][at * 4 + 2] = dz; se[e][at * 4 + 3] = ln;
        }
    }
    __syncthreads();
    if (tid < 32) {
        const int h = tid >> 4, f = tid & 15;
        float s = 0.f;
        for (int e = 0; e < 8; ++e) s += se[h * 8 + e][f];
        sm0[h][f] = s * 0.125f;
    }
    if (tid < 128) {
        const int j = tid >> 3, h = (tid >> 2) & 1, f = tid & 3;
        float s = 0.f;
        for (int i2 = 0; i2 < 8; ++i2) s += pin[j][h * 8 + i2][f];
        pm0[j][h][f] = s * 0.125f;
    }
    __syncthreads();
    for (int t = tid; t < 16 * 56; t += 256) {
        const int e = t / 56, k = t % 56;
        float v;
        if (k < 16)      v = se[e][k];
        else if (k < 32) v = sm0[0][k - 16];
        else if (k < 48) v = sm0[1][k - 32];
        else if (k < 52) v = pm0[e][0][k - 48];
        else             v = pm0[e][1][k - 52];
        blk[e][k] = v;
    }
    __syncthreads();

    const int n = tid;
    float acc[16];
#pragma unroll
    for (int e = 0; e < 16; ++e) acc[e] = sb0[n];
    for (int k = 0; k < 56; k += 4) {
        float w0 = sW0[(k + 0) * 256 + n];
        float w1 = sW0[(k + 1) * 256 + n];
        float w2 = sW0[(k + 2) * 256 + n];
        float w3 = sW0[(k + 3) * 256 + n];
#pragma unroll
        for (int e = 0; e < 16; ++e) {
            float4 s4 = *(const float4*)&blk[e][k];
            acc[e] += s4.x * w0 + s4.y * w1 + s4.z * w2 + s4.w * w3;
        }
    }
    _Float16* sh_b = s_hi + (size_t)b * 4096;
    _Float16* sl_b = s_lo + (size_t)b * 4096;
#pragma unroll
    for (int e = 0; e < 16; ++e) {
        float v = fast_tanh(acc[e]);
        _Float16 hi, lo; split16(v, hi, lo);
        sh_b[e * 256 + n] = hi;
        sl_b[e * 256 + n] = lo;
    }
}

// ---------------------------------------------------------------------------
// Shared (row-constant) part, exact fp32:
//   Zsh[b][n] = bias[n] + mu_b . W[256:512][:,n] + md_b . W[512:768][:,n]
// Block = 4 walkers, 256 threads, grid 512.
// ---------------------------------------------------------------------------
__global__ __launch_bounds__(256) void k_shared(
    const _Float16* __restrict__ s_hi, const _Float16* __restrict__ s_lo,
    const float* __restrict__ W, const float* __restrict__ bias,
    float* __restrict__ Zsh)
{
    const int b0  = blockIdx.x * 4;
    const int tid = threadIdx.x;
    __shared__ float mean[4][2][256];   // 8 KB

    {
        const int v0 = tid * 8;          // covers 4*2*256 = 2048 outputs
        const int w  = v0 >> 9, h = (v0 >> 8) & 1, k0 = v0 & 255;
        float acc[8] = {0.f, 0.f, 0.f, 0.f, 0.f, 0.f, 0.f, 0.f};
        for (int e = 0; e < 8; ++e) {
            const size_t base = ((size_t)(b0 + w) * 16 + h * 8 + e) * 256 + k0;
#pragma unroll
            for (int kk = 0; kk < 8; ++kk)
                acc[kk] += (float)s_hi[base + kk] + (float)s_lo[base + kk];
        }
#pragma unroll
        for (int kk = 0; kk < 8; ++kk) mean[w][h][k0 + kk] = acc[kk] * 0.125f;
    }
    __syncthreads();

    const int w2 = tid >> 6;
    const int n0 = (tid & 63) * 4;
    float4 z = make_float4(bias[n0], bias[n0 + 1], bias[n0 + 2], bias[n0 + 3]);
#pragma unroll 4
    for (int k = 0; k < 256; ++k) {
        const float mu = mean[w2][0][k];
        const float md = mean[w2][1][k];
        float4 wmu = *(const float4*)&W[(256 + k) * 256 + n0];
        float4 wmd = *(const float4*)&W[(512 + k) * 256 + n0];
        z.x += mu * wmu.x + md * wmd.x;
        z.y += mu * wmu.y + md * wmd.y;
        z.z += mu * wmu.z + md * wmd.z;
        z.w += mu * wmu.w + md * wmd.w;
    }
    *(float4*)&Zsh[(size_t)(b0 + w2) * 256 + n0] = z;
}

// ---------------------------------------------------------------------------
// Split-f16 MFMA s-layer (per-electron part, K=320), 3-term split.
// Block = 4 walkers, 512 threads = 8 waves = 2 wave-groups. (R11-verbatim)
// ---------------------------------------------------------------------------
__global__ __launch_bounds__(512, 4) void k_gemm(
    _Float16* __restrict__ s_hi, _Float16* __restrict__ s_lo,
    const _Float16* __restrict__ pm_hi, const _Float16* __restrict__ pm_lo,
    const _Float16* __restrict__ Bhi, const _Float16* __restrict__ Blo,
    const float* __restrict__ Zsh,
    int is_final)
{
    const int tid  = threadIdx.x;
    const int lane = tid & 63;
    const int wv   = tid >> 6;        // 0..7
    const int wg   = wv >> 2;         // walker group (2 walkers each)
    const int wv4  = wv & 3;          // n-tile group
    const int m16  = lane & 15;
    const int quad = lane >> 4;
    const int wb   = blockIdx.x * 4 + wg * 2;
    const int n0   = wv4 * 64;

    f32x4 acc[2][4];
#pragma unroll
    for (int mt = 0; mt < 2; ++mt)
#pragma unroll
        for (int nt = 0; nt < 4; ++nt) acc[mt][nt] = (f32x4){0.f, 0.f, 0.f, 0.f};

    int aS[2], aP[2];
#pragma unroll
    for (int mt = 0; mt < 2; ++mt) {
        aS[mt] = ((wb + mt) * 16 + m16) * 256 + quad * 8;
        aP[mt] = ((wb + mt) * 16 + m16) * 64  + quad * 8;
    }
    const _Float16* Bhw = Bhi + (size_t)(wv4 * 4) * 512 + (size_t)lane * 8;
    const _Float16* Blw = Blo + (size_t)(wv4 * 4) * 512 + (size_t)lane * 8;

    // ---- s part: kc 0..7
#pragma unroll
    for (int kc = 0; kc < 8; ++kc) {
        f16x8 ah[2], al[2];
#pragma unroll
        for (int mt = 0; mt < 2; ++mt) {
            ah[mt] = *(const f16x8*)(s_hi + aS[mt] + kc * 32);
            al[mt] = *(const f16x8*)(s_lo + aS[mt] + kc * 32);
        }
#pragma unroll
        for (int nt = 0; nt < 4; ++nt) {
            f16x8 bh = *(const f16x8*)(Bhw + (size_t)kc * 8192 + nt * 512);
            f16x8 bl = *(const f16x8*)(Blw + (size_t)kc * 8192 + nt * 512);
#pragma unroll
            for (int mt = 0; mt < 2; ++mt) {
                acc[mt][nt] = __builtin_amdgcn_mfma_f32_16x16x32_f16(ah[mt], bh, acc[mt][nt], 0, 0, 0);
                acc[mt][nt] = __builtin_amdgcn_mfma_f32_16x16x32_f16(ah[mt], bl, acc[mt][nt], 0, 0, 0);
                acc[mt][nt] = __builtin_amdgcn_mfma_f32_16x16x32_f16(al[mt], bh, acc[mt][nt], 0, 0, 0);
            }
        }
    }
    // ---- p part: kc 8..9 (pu, pd), pm hi/lo 3-term
#pragma unroll
    for (int h = 0; h < 2; ++h) {
        f16x8 ah[2], al[2];
#pragma unroll
        for (int mt = 0; mt < 2; ++mt) {
            ah[mt] = *(const f16x8*)(pm_hi + aP[mt] + h * 32);
            al[mt] = *(const f16x8*)(pm_lo + aP[mt] + h * 32);
        }
#pragma unroll
        for (int nt = 0; nt < 4; ++nt) {
            f16x8 bh = *(const f16x8*)(Bhw + (size_t)(8 + h) * 8192 + nt * 512);
            f16x8 bl = *(const f16x8*)(Blw + (size_t)(8 + h) * 8192 + nt * 512);
#pragma unroll
            for (int mt = 0; mt < 2; ++mt) {
                acc[mt][nt] = __builtin_amdgcn_mfma_f32_16x16x32_f16(ah[mt], bh, acc[mt][nt], 0, 0, 0);
                acc[mt][nt] = __builtin_amdgcn_mfma_f32_16x16x32_f16(ah[mt], bl, acc[mt][nt], 0, 0, 0);
                acc[mt][nt] = __builtin_amdgcn_mfma_f32_16x16x32_f16(al[mt], bh, acc[mt][nt], 0, 0, 0);
            }
        }
    }

    __syncthreads();   // all A reads complete before in-place rewrite

    // ---- epilogue
#pragma unroll
    for (int mt = 0; mt < 2; ++mt) {
#pragma unroll
        for (int nt = 0; nt < 4; ++nt) {
            const int n  = n0 + nt * 16 + m16;
            const float zv = Zsh[(size_t)(wb + mt) * 256 + n];
            const int rowbase = (wb + mt) * 16 + quad * 4;
#pragma unroll
            for (int reg = 0; reg < 4; ++reg) {
                const int idx = (rowbase + reg) * 256 + n;
                float t = fast_tanh(acc[mt][nt][reg] + zv);
                if (!is_final) t += (float)s_hi[idx] + (float)s_lo[idx];
                _Float16 hi, lo; split16(t, hi, lo);
                s_hi[idx] = hi;
                s_lo[idx] = lo;
            }
        }
    }
}

// ---------------------------------------------------------------------------
// FUSED orbitals (split-f16 MFMA, 4-term = exact-to-fp32) + slogdet + lse.
// Block = 2 walkers, 256 threads = 4 waves; wave = (spin = wv>>1, nhalf = wv&1).
// A rows: m16 -> walker (m16>>3), electron spin*8 + (m16&7); A direct from
// global s hi/lo (b128). B pre-packed oB frags. D: row=quad*4+reg -> (walker,
// electron), col -> c = nhalf*64 + nt*16 + m16 -> (det = c&15, jrow = c>>4).
// Orbitals -> LDS orbL[w][spin][det][66] (stride 66 breaks 16-way banking);
// det phase: threads 0-31 = (walker, det), shuffles within 16-lane groups.
// ---------------------------------------------------------------------------
__device__ __forceinline__ void slogdet8(float M[8][8], float& sgn_out, float& ld_out) {
    float sgn = 1.f, ld = 0.f;
#pragma unroll
    for (int k = 0; k < 8; ++k) {
        float best = fabsf(M[k][k]);
        int p = k;
#pragma unroll
        for (int rr = k + 1; rr < 8; ++rr) {
            float v = fabsf(M[rr][k]);
            if (v > best) { best = v; p = rr; }
        }
        if (p != k) sgn = -sgn;
#pragma unroll
        for (int rr = k + 1; rr < 8; ++rr) {
            bool sw = (rr == p);
#pragma unroll
            for (int cc = k; cc < 8; ++cc) {
                float x = M[k][cc], y = M[rr][cc];
                M[k][cc]  = sw ? y : x;
                M[rr][cc] = sw ? x : y;
            }
        }
        float piv = M[k][k];
        if (piv < 0.f) sgn = -sgn;
        ld += logf(fabsf(piv));
        float inv = 1.f / piv;
#pragma unroll
        for (int rr = k + 1; rr < 8; ++rr) {
            float f = M[rr][k] * inv;
#pragma unroll
            for (int cc = k + 1; cc < 8; ++cc) M[rr][cc] -= f * M[k][cc];
        }
    }
    sgn_out = sgn; ld_out = ld;
}

__global__ __launch_bounds__(256) void k_orbdet(
    const float* __restrict__ r, const float* __restrict__ a,
    const _Float16* __restrict__ s_hi, const _Float16* __restrict__ s_lo,
    const _Float16* __restrict__ oBhi, const _Float16* __restrict__ oBlo,
    const float* __restrict__ wub, const float* __restrict__ wdb,
    const float* __restrict__ wfW,
    float* __restrict__ out)
{
    const int wb   = blockIdx.x * 2;   // walkers wb, wb+1
    const int tid  = threadIdx.x;
    const int lane = tid & 63;
    const int wv   = tid >> 6;         // 0..3
    const int spin = wv >> 1;
    const int nhalf = wv & 1;
    const int m16  = lane & 15;
    const int quad = lane >> 4;

    __shared__ float orbL[2][2][16][66];  // [walker][spin][det][jrow*8+e], 33.8 KB
    __shared__ float envl[2][16];

    if (tid < 32) {
        const int w = tid >> 4, e = tid & 15;
        float ex = 0.f;
#pragma unroll
        for (int at = 0; at < 4; ++at) {
            float dx = r[(wb + w) * 48 + e * 3 + 0] - a[at * 3 + 0];
            float dy = r[(wb + w) * 48 + e * 3 + 1] - a[at * 3 + 1];
            float dz = r[(wb + w) * 48 + e * 3 + 2] - a[at * 3 + 2];
            ex += __expf(-sqrtf(dx * dx + dy * dy + dz * dz));
        }
        envl[w][e] = ex;
    }

    // ---- orbital GEMM: M=16 (2 walkers x 8 spin-electrons), N=64, K=256
    const int aBase = ((wb + (m16 >> 3)) * 16 + spin * 8 + (m16 & 7)) * 256 + quad * 8;

    f32x4 acc[4];
#pragma unroll
    for (int nt = 0; nt < 4; ++nt) acc[nt] = (f32x4){0.f, 0.f, 0.f, 0.f};

#pragma unroll
    for (int kc = 0; kc < 8; ++kc) {
        f16x8 ah = *(const f16x8*)(s_hi + aBase + kc * 32);
        f16x8 al = *(const f16x8*)(s_lo + aBase + kc * 32);
#pragma unroll
        for (int nt = 0; nt < 4; ++nt) {
            const size_t bo = (((size_t)spin * 8 + kc) * 8 + nhalf * 4 + nt) * 512 + (size_t)lane * 8;
            f16x8 bh = *(const f16x8*)(oBhi + bo);
            f16x8 bl = *(const f16x8*)(oBlo + bo);
            acc[nt] = __builtin_amdgcn_mfma_f32_16x16x32_f16(ah, bh, acc[nt], 0, 0, 0);
            acc[nt] = __builtin_amdgcn_mfma_f32_16x16x32_f16(ah, bl, acc[nt], 0, 0, 0);
            acc[nt] = __builtin_amdgcn_mfma_f32_16x16x32_f16(al, bh, acc[nt], 0, 0, 0);
            acc[nt] = __builtin_amdgcn_mfma_f32_16x16x32_f16(al, bl, acc[nt], 0, 0, 0);
        }
    }
    __syncthreads();   // envl visible to all waves

    // ---- epilogue: + bias, * env, scatter to LDS
    const float* bm = spin ? wdb : wub;
#pragma unroll
    for (int nt = 0; nt < 4; ++nt) {
        const int c = nhalf * 64 + nt * 16 + m16;
        const float bv = bm[c];
        const int d = c & 15;        // == m16
        const int jrow = c >> 4;     // == nhalf*4 + nt
#pragma unroll
        for (int reg = 0; reg < 4; ++reg) {
            const int m = quad * 4 + reg;
            const int w = m >> 3, el = m & 7;
            orbL[w][spin][d][jrow * 8 + el] = (acc[nt][reg] + bv) * envl[w][spin * 8 + el];
        }
    }
    __syncthreads();

    // ---- determinants: threads 0-31 = (walker, det)
    if (tid < 32) {
        const int w = tid >> 4, d = tid & 15;
        float M[8][8];
#pragma unroll
        for (int rr = 0; rr < 8; ++rr)
#pragma unroll
            for (int cc = 0; cc < 8; ++cc) M[rr][cc] = orbL[w][0][d][rr * 8 + cc];
        float s1, l1; slogdet8(M, s1, l1);
#pragma unroll
        for (int rr = 0; rr < 8; ++rr)
#pragma unroll
            for (int cc = 0; cc < 8; ++cc) M[rr][cc] = orbL[w][1][d][rr * 8 + cc];
        float s2, l2; slogdet8(M, s2, l2);
        float sgn = s1 * s2;
        float ld  = l1 + l2;

        float m = ld;
        m = fmaxf(m, __shfl_xor(m, 1));
        m = fmaxf(m, __shfl_xor(m, 2));
        m = fmaxf(m, __shfl_xor(m, 4));
        m = fmaxf(m, __shfl_xor(m, 8));
        float sub = sgn * __expf(ld - m) * wfW[d];
        sub += __shfl_xor(sub, 1);
        sub += __shfl_xor(sub, 2);
        sub += __shfl_xor(sub, 4);
        sub += __shfl_xor(sub, 8);
        if (d == 0) out[wb + w] = logf(fabsf(sub)) + m;
    }
}

// ---------------------------------------------------------------------------
extern "C" void kernel_launch(void* const* d_in, const int* in_sizes, int n_in,
                              void* d_out, int out_size, void* d_ws, size_t ws_size,
                              hipStream_t stream) {
    (void)in_sizes; (void)n_in; (void)out_size; (void)ws_size;
    const float* r   = (const float*)d_in[0];
    const float* a   = (const float*)d_in[1];
    const float* sW0 = (const float*)d_in[2];
    const float* sb0 = (const float*)d_in[3];
    const float* sW  = (const float*)d_in[4];
    const float* sb  = (const float*)d_in[5];
    const float* pW0 = (const float*)d_in[6];
    const float* pb0 = (const float*)d_in[7];
    const float* pW  = (const float*)d_in[8];
    const float* pb  = (const float*)d_in[9];
    const float* vW  = (const float*)d_in[10];
    const float* vb  = (const float*)d_in[11];
    const float* wuW = (const float*)d_in[12];
    const float* wub = (const float*)d_in[13];
    const float* wdW = (const float*)d_in[14];
    const float* wdb = (const float*)d_in[15];
    const float* wfW = (const float*)d_in[16];
    float* out = (float*)d_out;

    // workspace layout (bytes), total 79,511,552 (< 79,691,776 known-safe)
    char* wsb = (char*)d_ws;
    _Float16* s_hi  = (_Float16*)(wsb + 0);          // 16,777,216
    _Float16* s_lo  = (_Float16*)(wsb + 16777216);   // 16,777,216
    _Float16* pm_hi = (_Float16*)(wsb + 33554432);   // 20,971,520 (5 stages)
    _Float16* pm_lo = (_Float16*)(wsb + 54525952);   // 20,971,520
    float*    Zsh   = (float*)   (wsb + 75497472);   //  2,097,152
    _Float16* Bhi   = (_Float16*)(wsb + 77594624);   //    819,200
    _Float16* Blo   = (_Float16*)(wsb + 78413824);   //    819,200
    _Float16* pBhi  = (_Float16*)(wsb + 79233024);   //      8,192
    _Float16* pBlo  = (_Float16*)(wsb + 79241216);   //      8,192
    _Float16* oBhi  = (_Float16*)(wsb + 79249408);   //    131,072
    _Float16* oBlo  = (_Float16*)(wsb + 79380480);   //    131,072

    k_prep_w<<<50, 256, 0, stream>>>(sW, vW, Bhi, Blo);
    k_prep_p<<<4, 128, 0, stream>>>(pW, pBhi, pBlo);
    k_prep_orb<<<16, 256, 0, stream>>>(wuW, wdW, oBhi, oBlo);
    k_pstream<<<NB, 1024, 0, stream>>>(r, pW0, pb0, pb, pBhi, pBlo, pm_hi, pm_lo);
    k_s0<<<NB, 256, 0, stream>>>(r, a, sW0, sb0, s_hi, s_lo);
    for (int l = 0; l < 4; ++l) {
        k_shared<<<NB / 4, 256, 0, stream>>>(s_hi, s_lo, sW + (size_t)l * 212992,
                                             sb + l * 256, Zsh);
        k_gemm<<<NB / 4, 512, 0, stream>>>(s_hi, s_lo,
                                           pm_hi + (size_t)l * PM_STAGE,
                                           pm_lo + (size_t)l * PM_STAGE,
                                           Bhi + (size_t)l * BPK_L,
                                           Blo + (size_t)l * BPK_L,
                                           Zsh, 0);
    }
    k_shared<<<NB / 4, 256, 0, stream>>>(s_hi, s_lo, vW, vb, Zsh);
    k_gemm<<<NB / 4, 512, 0, stream>>>(s_hi, s_lo,
                                       pm_hi + (size_t)4 * PM_STAGE,
                                       pm_lo + (size_t)4 * PM_STAGE,
                                       Bhi + (size_t)4 * BPK_L,
                                       Blo + (size_t)4 * BPK_L,
                                       Zsh, 1);
    k_orbdet<<<NB / 2, 256, 0, stream>>>(r, a, s_hi, s_lo, oBhi, oBlo,
                                         wub, wdb, wfW, out);
}